// Round 5
// baseline (298.920 us; speedup 1.0000x reference)
//
#include <hip/hip_runtime.h>
#include <hip/hip_cooperative_groups.h>

namespace cg = cooperative_groups;

#define B_RS 4

// workspace float offsets
#define A_K64 0          // 8 reps x 1024 ull (fkey<<32 | idx)      -> 16384 fl
#define A_CNT 16384      // 8 x 1024 uint
#define A_SB  24576      // 8 x 1024 float
#define A_SP  32768      // 8 x 1024 float
#define A_LSE 40960      // 8 x 1024 float
#define A_QA  49152      // 1024
#define A_CF  50176      // 1024
#define A_OR  51200      // 1024 int
#define A_XLO 52224      // 1024 float4
#define A_XHI 56320      // 1024 float4
#define A_PSM 60416      // 1024
#define A_CY0 61440      // 4 rows x 256 float4 (-2x lo)
#define A_CY1 65536      // 4 rows x 256 float4 (-2x hi)
#define A_CCC 69632      // 4 rows x 256 float2 (ck2+1e-6, cf)
#define A_RC  71680      // 4 int rowcnt
#define A_NS  71684      // 8 reps x 8 (cnt,sum per row)
#define A_ACC 71748      // obj_cnt[4], obj_pen[4], att[4], rep[4]
#define A_QS  71808      // N
// A_PS = A_QS + N

__device__ __forceinline__ unsigned fkey(float f) {
    unsigned u = __float_as_uint(f);
    return ((int)u < 0) ? ~u : (u | 0x80000000u);
}
__device__ __forceinline__ float fdec(unsigned k) {
    unsigned u = ((int)k < 0) ? (k & 0x7fffffffu) : ~k;
    return __uint_as_float(u);
}

__global__ __launch_bounds__(256) void k_all(const float* __restrict__ beta,
                                             const float* __restrict__ coords,
                                             const int* __restrict__ asso,
                                             const int* __restrict__ rs,
                                             float* __restrict__ w,
                                             float* __restrict__ out, int N) {
    cg::grid_group grid = cg::this_grid();
    __shared__ float4 sY0[512];
    __shared__ float4 sY1[512];
    __shared__ float2 sCC[512];
    __shared__ float sBins[8];
    int t = threadIdx.x, bid = blockIdx.x;
    int tid = bid * 256 + t;
    int rs1 = rs[1], rs2 = rs[2], rs3 = rs[3];

    // ---- phase 0: zero tables ----
    if (tid < 49152) ((unsigned*)w)[tid] = 0u;
    if (tid < 84) ((unsigned*)w)[71680 + tid] = 0u;
    grid.sync();

    // ---- phase 1: per-point q/p, packed key|idx max, cnt/sb/sp, noise bins ----
    if (t < 8) sBins[t] = 0.f;
    __syncthreads();
    if (tid < N) {
        float b = beta[tid];
        int a = asso[tid];
        float bc = fminf(fmaxf(b, 0.f), 0.999f);
        float ath = 0.5f * __logf(__fdividef(1.f + bc, 1.f - bc));
        float at2 = ath * ath;
        w[A_QS + tid] = at2 + 0.1f;
        float pv = fmaxf(at2, 1e-6f);
        w[A_QS + N + tid] = pv;
        if (a >= 0) {
            int rp = bid & 7;
            unsigned long long pk = (((unsigned long long)fkey(b)) << 32) | (unsigned)tid;
            atomicMax((unsigned long long*)w + (rp << 10) + a, pk);
            atomicAdd((unsigned*)w + A_CNT + (rp << 10) + a, 1u);
            atomicAdd(w + A_SB + (rp << 10) + a, b);
            atomicAdd(w + A_SP + (rp << 10) + a, pv);
        } else {
            int r = (tid >= rs1) + (tid >= rs2) + (tid >= rs3);
            atomicAdd(&sBins[r * 2], 1.f);
            atomicAdd(&sBins[r * 2 + 1], b);
        }
    }
    __syncthreads();
    if (t < 8 && sBins[t] != 0.f) atomicAdd(w + A_NS + (bid & 7) * 8 + t, sBins[t]);
    grid.sync();

    // ---- phase 2: LSE sums (inline replica max for seg_max) ----
    if (tid < N) {
        int a = asso[tid];
        if (a >= 0) {
            float b = beta[tid];
            unsigned mk = 0u;
#pragma unroll
            for (int rp = 0; rp < 8; ++rp) {
                unsigned v = ((unsigned*)w)[(((rp << 10) + a) << 1) + 1];
                mk = v > mk ? v : mk;
            }
            float m = fdec(mk);
            float e = __expf((b - m) * 1000.f);
            atomicAdd(w + A_LSE + ((bid & 7) << 10) + a, e);
        }
    }
    grid.sync();

    // ---- phase 3: per-cluster finalize + compaction ----
    if (tid < 1024) {
        int k = tid;
        unsigned long long k64 = 0ull;
        unsigned cnt = 0u;
        float sb = 0.f, sp = 0.f, ls = 0.f;
#pragma unroll
        for (int rp = 0; rp < 8; ++rp) {
            unsigned long long v = ((unsigned long long*)w)[(rp << 10) + k];
            k64 = v > k64 ? v : k64;
            cnt += ((unsigned*)w)[A_CNT + (rp << 10) + k];
            sb += w[A_SB + (rp << 10) + k];
            sp += w[A_SP + (rp << 10) + k];
            ls += w[A_LSE + (rp << 10) + k];
        }
        bool ov = cnt > 0u;
        int ai = (int)(unsigned)(k64 & 0xffffffffull);
        float4 x0 = ((const float4*)coords)[ai * 2];
        float4 x1 = ((const float4*)coords)[ai * 2 + 1];
        float ba = beta[ai];
        float bca = fminf(fmaxf(ba, 0.f), 0.999f);
        float ata = atanhf(bca);
        float qa = ov ? ata * ata + 0.1f : 0.f;
        int orr = (ai >= rs1) + (ai >= rs2) + (ai >= rs3);
        float cf = qa / fmaxf((float)cnt, 1.f);
        w[A_QA + k] = qa;
        w[A_CF + k] = cf;
        ((int*)w)[A_OR + k] = orr;
        ((float4*)(w + A_XLO))[k] = x0;
        ((float4*)(w + A_XHI))[k] = x1;
        w[A_PSM + k] = sp;
        float m = ov ? fdec((unsigned)(k64 >> 32)) : 0.f;
        float lse = m + 0.001f * logf(ls + 1e-30f);
        float sbc = fminf(fmaxf(sb, 0.f), 1.f);
        float bpen = 1.f - lse + (1.f - sbc);
        if (ov) {
            atomicAdd(w + A_ACC + orr, 1.f);
            atomicAdd(w + A_ACC + 4 + orr, bpen);
            int slot = atomicAdd((int*)w + A_RC + orr, 1);
            int idx = (orr << 8) + slot;
            ((float4*)(w + A_CY0))[idx] = make_float4(-2.f * x0.x, -2.f * x0.y, -2.f * x0.z, -2.f * x0.w);
            ((float4*)(w + A_CY1))[idx] = make_float4(-2.f * x1.x, -2.f * x1.y, -2.f * x1.z, -2.f * x1.w);
            float ck2 = x0.x * x0.x + x0.y * x0.y + x0.z * x0.z + x0.w * x0.w +
                        x1.x * x1.x + x1.y * x1.y + x1.z * x1.z + x1.w * x1.w;
            ((float2*)(w + A_CCC))[idx] = make_float2(ck2 + 1e-6f, cf);
        }
    }
    grid.sync();

    // ---- phase 4: N x K_row repulsion + fused epilogue ----
    int nch = (N + 511) >> 9;
    if (t < 8) sBins[t] = 0.f;
    int base = bid << 9;
    int r0 = 0, rl = 0, n0 = 0, n1 = 0;
    if (bid < nch) {
        r0 = (base >= rs1) + (base >= rs2) + (base >= rs3);
        int lastp = min(base + 511, N - 1);
        rl = (lastp >= rs1) + (lastp >= rs2) + (lastp >= rs3);
        n0 = ((int*)w)[A_RC + r0];
        if (t < n0) {
            int idx = (r0 << 8) + t;
            sY0[t] = ((const float4*)(w + A_CY0))[idx];
            sY1[t] = ((const float4*)(w + A_CY1))[idx];
            sCC[t] = ((const float2*)(w + A_CCC))[idx];
        }
        if (rl != r0) {
            n1 = ((int*)w)[A_RC + rl];
            if (t < n1) {
                int idx = (rl << 8) + t;
                sY0[n0 + t] = ((const float4*)(w + A_CY0))[idx];
                sY1[n0 + t] = ((const float4*)(w + A_CY1))[idx];
                sCC[n0 + t] = ((const float2*)(w + A_CCC))[idx];
            }
        }
    }
    __syncthreads();
    if (bid < nch) {
        int i0 = base + 2 * t, i1 = i0 + 1;
        bool in0 = i0 < N, in1 = i1 < N;
        float4 c00, c01, c10, c11;
        float cn20 = 0.f, cn21 = 0.f;
        int rr0 = r0, rr1 = r0;
        if (in0) {
            const float4* cp = (const float4*)(coords + (size_t)i0 * 8);
            c00 = cp[0]; c01 = cp[1];
            cn20 = c00.x * c00.x + c00.y * c00.y + c00.z * c00.z + c00.w * c00.w +
                   c01.x * c01.x + c01.y * c01.y + c01.z * c01.z + c01.w * c01.w;
            rr0 = (i0 >= rs1) + (i0 >= rs2) + (i0 >= rs3);
        }
        if (in1) {
            const float4* cp = (const float4*)(coords + (size_t)i1 * 8);
            c10 = cp[0]; c11 = cp[1];
            cn21 = c10.x * c10.x + c10.y * c10.y + c10.z * c10.z + c10.w * c10.w +
                   c11.x * c11.x + c11.y * c11.y + c11.z * c11.z + c11.w * c11.w;
            rr1 = (i1 >= rs1) + (i1 >= rs2) + (i1 >= rs3);
        }
        int s0 = (rr0 == r0) ? 0 : n0, e0 = (rr0 == r0) ? n0 : n0 + n1;
        int s1 = (rr1 == r0) ? 0 : n0, e1 = (rr1 == r0) ? n0 : n0 + n1;
        float acc0 = 0.f, acc1 = 0.f;
        if (in0 && in1 && s0 == s1) {
#pragma unroll 2
            for (int j = s0; j < e0; ++j) {
                float4 y0 = sY0[j];
                float4 y1 = sY1[j];
                float2 cx = sCC[j];
                float d0 = cn20 + cx.x, d1 = cn21 + cx.x;
                d0 = fmaf(y0.x, c00.x, d0); d1 = fmaf(y0.x, c10.x, d1);
                d0 = fmaf(y0.y, c00.y, d0); d1 = fmaf(y0.y, c10.y, d1);
                d0 = fmaf(y0.z, c00.z, d0); d1 = fmaf(y0.z, c10.z, d1);
                d0 = fmaf(y0.w, c00.w, d0); d1 = fmaf(y0.w, c10.w, d1);
                d0 = fmaf(y1.x, c01.x, d0); d1 = fmaf(y1.x, c11.x, d1);
                d0 = fmaf(y1.y, c01.y, d0); d1 = fmaf(y1.y, c11.y, d1);
                d0 = fmaf(y1.z, c01.z, d0); d1 = fmaf(y1.z, c11.z, d1);
                d0 = fmaf(y1.w, c01.w, d0); d1 = fmaf(y1.w, c11.w, d1);
                d0 = fmaxf(d0, 1e-6f); d1 = fmaxf(d1, 1e-6f);
                float v0 = fmaxf(1.f - sqrtf(d0), 0.f);
                float v1 = fmaxf(1.f - sqrtf(d1), 0.f);
                acc0 = fmaf(v0, cx.y, acc0);
                acc1 = fmaf(v1, cx.y, acc1);
            }
        } else {
            for (int j = s0; in0 && j < e0; ++j) {
                float4 y0 = sY0[j]; float4 y1 = sY1[j]; float2 cx = sCC[j];
                float d = cn20 + cx.x;
                d = fmaf(y0.x, c00.x, d); d = fmaf(y0.y, c00.y, d);
                d = fmaf(y0.z, c00.z, d); d = fmaf(y0.w, c00.w, d);
                d = fmaf(y1.x, c01.x, d); d = fmaf(y1.y, c01.y, d);
                d = fmaf(y1.z, c01.z, d); d = fmaf(y1.w, c01.w, d);
                d = fmaxf(d, 1e-6f);
                acc0 = fmaf(fmaxf(1.f - sqrtf(d), 0.f), cx.y, acc0);
            }
            for (int j = s1; in1 && j < e1; ++j) {
                float4 y0 = sY0[j]; float4 y1 = sY1[j]; float2 cx = sCC[j];
                float d = cn21 + cx.x;
                d = fmaf(y0.x, c10.x, d); d = fmaf(y0.y, c10.y, d);
                d = fmaf(y0.z, c10.z, d); d = fmaf(y0.w, c10.w, d);
                d = fmaf(y1.x, c11.x, d); d = fmaf(y1.y, c11.y, d);
                d = fmaf(y1.z, c11.z, d); d = fmaf(y1.w, c11.w, d);
                d = fmaxf(d, 1e-6f);
                acc1 = fmaf(fmaxf(1.f - sqrtf(d), 0.f), cx.y, acc1);
            }
        }
        // fused epilogue
        float attv[2] = {0.f, 0.f}, repv[2] = {0.f, 0.f};
        int rv[2] = {rr0, rr1};
        int2 a2 = make_int2(-1, -1);
        if (in1) a2 = *(const int2*)(asso + i0);
        else if (in0) a2.x = asso[i0];
#pragma unroll
        for (int p = 0; p < 2; ++p) {
            bool in = p ? in1 : in0;
            if (!in) continue;
            int i = i0 + p;
            int r = p ? rr1 : rr0;
            int aa = p ? a2.y : a2.x;
            float acc = p ? acc1 : acc0;
            float4 cA = p ? c10 : c00;
            float4 cB = p ? c11 : c01;
            float cn2 = p ? cn21 : cn20;
            float q = w[A_QS + i];
            float pv = w[A_QS + N + i];
            bool valid = aa >= 0;
            int kk = valid ? aa : 0;
            float att = 0.f;
            if (valid) {
                float4 xk0 = ((const float4*)(w + A_XLO))[kk];
                float4 xk1 = ((const float4*)(w + A_XHI))[kk];
                float qak = w[A_QA + kk];
                float d0 = cA.x - xk0.x, d1 = cA.y - xk0.y, d2 = cA.z - xk0.z, d3 = cA.w - xk0.w;
                float d4 = cB.x - xk1.x, d5 = cB.y - xk1.y, d6 = cB.z - xk1.z, d7 = cB.w - xk1.w;
                float dsq = d0 * d0 + d1 * d1 + d2 * d2 + d3 * d3 +
                            d4 * d4 + d5 * d5 + d6 * d6 + d7 * d7;
                att = q * qak * dsq;
                int ork = ((const int*)w)[A_OR + kk];
                if (ork == r) {
                    float ck2 = xk0.x * xk0.x + xk0.y * xk0.y + xk0.z * xk0.z + xk0.w * xk0.w +
                                xk1.x * xk1.x + xk1.y * xk1.y + xk1.z * xk1.z + xk1.w * xk1.w;
                    float dotk = cA.x * xk0.x + cA.y * xk0.y + cA.z * xk0.z + cA.w * xk0.w +
                                 cB.x * xk1.x + cB.y * xk1.y + cB.z * xk1.z + cB.w * xk1.w;
                    float d = fmaxf(cn2 + ck2 - 2.f * dotk, 0.f) + 1e-6f;
                    float vk = fmaxf(1.f - sqrtf(d), 0.f);
                    acc -= vk * w[A_CF + kk];
                }
            }
            float rp = q * acc;
            attv[p] = att; repv[p] = rp;
            float psum = w[A_PSM + kk];
            float ocnt = w[A_ACC + r];
            float pl = valid ? pv / fmaxf(psum, 1e-6f) / fmaxf(ocnt, 1.f) * 0.25f : 0.f;
            out[3 + i] = pl;
            out[3 + N + i] = att + rp;
        }
        // row reduction
        int lane = t & 63;
        int rA = __shfl(rv[0], 0);
        bool uni = __all(rv[0] == rA) && __all(rv[1] == rA);
        if (uni) {
            float aS = attv[0] + attv[1], rS = repv[0] + repv[1];
#pragma unroll
            for (int o = 32; o; o >>= 1) { aS += __shfl_xor(aS, o); rS += __shfl_xor(rS, o); }
            if (lane == 0) { atomicAdd(&sBins[rA], aS); atomicAdd(&sBins[4 + rA], rS); }
        } else {
#pragma unroll
            for (int p = 0; p < 2; ++p) {
                if (i0 + p < N) {
                    atomicAdd(&sBins[rv[p]], attv[p]);
                    atomicAdd(&sBins[4 + rv[p]], repv[p]);
                }
            }
        }
    }
    __syncthreads();
    if (t < 8 && sBins[t] != 0.f) atomicAdd(w + A_ACC + 8 + t, sBins[t]);
    grid.sync();

    // ---- phase 5: final scalars ----
    if (tid == 0) {
        float lv = 0.f, lr = 0.f, lb = 0.f;
        for (int r = 0; r < B_RS; ++r) {
            float len = (float)(rs[r + 1] - rs[r]);
            lv += w[A_ACC + 8 + r] / len;
            lr += w[A_ACC + 12 + r] / len;
            float oc = w[A_ACC + r], op = w[A_ACC + 4 + r];
            float nc = 0.f, nsm = 0.f;
            for (int rp = 0; rp < 8; ++rp) {
                nc += w[A_NS + rp * 8 + 2 * r];
                nsm += w[A_NS + rp * 8 + 2 * r + 1];
            }
            lb += op / fmaxf(oc, 1.f) + nsm / fmaxf(nc, 1.f);
        }
        out[0] = lv * 0.25f;
        out[1] = lr * 0.25f;
        out[2] = lb * 0.25f;
    }
}

extern "C" void kernel_launch(void* const* d_in, const int* in_sizes, int n_in,
                              void* d_out, int out_size, void* d_ws, size_t ws_size,
                              hipStream_t stream) {
    const float* beta = (const float*)d_in[0];
    const float* coords = (const float*)d_in[1];
    const int* asso = (const int*)d_in[2];
    const int* rs = (const int*)d_in[3];
    int N = in_sizes[0];
    float* w = (float*)d_ws;
    float* out = (float*)d_out;
    int gb = 2 * ((N + 511) / 512);
    if (gb < 4) gb = 4;
    void* args[] = {(void*)&beta, (void*)&coords, (void*)&asso, (void*)&rs,
                    (void*)&w, (void*)&out, (void*)&N};
    (void)hipLaunchCooperativeKernel((const void*)k_all, dim3(gb), dim3(256), args, 0, stream);
}

// Round 6
// 79.398 us; speedup vs baseline: 3.7648x; 3.7648x over previous
//
#include <hip/hip_runtime.h>

#define B_RS 4

// workspace float offsets
#define A_K64  0        // 8 reps x 1024 u64 packed (fkey<<32 | idx)
#define A_CNT  16384    // 8 x 1024 u32
#define A_SB   24576    // 8 x 1024 f32
#define A_SP   32768    // 8 x 1024 f32
#define A_LSE  40960    // 8 x 1024 f32   (zero region A: u32 [0, 49152))
#define A_QA   49152    // 1024
#define A_CF   50176    // 1024
#define A_OR   51200    // 1024 int
#define A_XLO  52224    // 1024 float4
#define A_XHI  56320    // 1024 float4
#define A_PSM  60416    // 1024
#define A_KEYM 61440    // 1024 u32 merged seg-max key
#define A_SBM  62464    // 1024 merged sum_b
#define A_NKM  63488    // 1024 u32 merged count
#define A_CY0  64512    // 4 rows x 256 float4 (-2x lo)
#define A_CY1  68608    // 4 rows x 256 float4 (-2x hi)
#define A_CCC  72704    // 4 rows x 256 float2 (ck2+1e-6, cf)
#define A_RC   74752    // 4 int row cluster counts
#define A_NS   74756    // 8 reps x 8 (noise cnt,sum per row)   (zero region B: u32 [74752, 74836))
#define A_ACC  74820    // obj_cnt[4] (+12 spare)
#define A_QS   74848    // q[N], then p[N], then p6 partials nb*8

__device__ __forceinline__ unsigned fkey(float f) {
    unsigned u = __float_as_uint(f);
    return ((int)u < 0) ? ~u : (u | 0x80000000u);
}
__device__ __forceinline__ float fdec(unsigned k) {
    unsigned u = ((int)k < 0) ? (k & 0x7fffffffu) : ~k;
    return __uint_as_float(u);
}

__global__ __launch_bounds__(256) void k_init(float* __restrict__ w) {
    int tid = blockIdx.x * 256 + threadIdx.x;
    if (tid < 12288) ((uint4*)w)[tid] = make_uint4(0u, 0u, 0u, 0u);
    else if (tid - 12288 < 84) ((unsigned*)w)[74752 + (tid - 12288)] = 0u;
}

// ---- P1: per-point q/p, packed (key|idx) max, cnt/sum_b/p_sum, noise bins ----
__global__ __launch_bounds__(512) void k_p1(const float* __restrict__ beta,
                                            const int* __restrict__ asso,
                                            const int* __restrict__ rs,
                                            float* __restrict__ w, int N) {
    __shared__ float ns[8];
    int t = threadIdx.x;
    if (t < 8) ns[t] = 0.f;
    int rs1 = rs[1], rs2 = rs[2], rs3 = rs[3];
    __syncthreads();
    int i = blockIdx.x * 512 + t;
    int rp = blockIdx.x & 7;
    if (i < N) {
        float b = beta[i];
        int a = asso[i];
        float bc = fminf(fmaxf(b, 0.f), 0.999f);
        float ath = 0.5f * __logf(__fdividef(1.f + bc, 1.f - bc));
        float at2 = ath * ath;
        w[A_QS + i] = at2 + 0.1f;
        float pv = fmaxf(at2, 1e-6f);
        w[A_QS + N + i] = pv;
        if (a >= 0) {
            unsigned long long pk = (((unsigned long long)fkey(b)) << 32) | (unsigned)i;
            atomicMax((unsigned long long*)w + (rp << 10) + a, pk);
            atomicAdd((unsigned*)w + A_CNT + (rp << 10) + a, 1u);
            atomicAdd(w + A_SB + (rp << 10) + a, b);
            atomicAdd(w + A_SP + (rp << 10) + a, pv);
        } else {
            int r = (i >= rs1) + (i >= rs2) + (i >= rs3);
            atomicAdd(&ns[2 * r], 1.f);
            atomicAdd(&ns[2 * r + 1], b);
        }
    }
    __syncthreads();
    if (t < 8 && ns[t] != 0.f) atomicAdd(w + A_NS + rp * 8 + t, ns[t]);
}

// ---- M1: merge replicas, per-cluster finalize, row compaction (4 blocks) ----
__global__ __launch_bounds__(256) void k_m1(const float* __restrict__ beta,
                                            const float* __restrict__ coords,
                                            const int* __restrict__ rs,
                                            float* __restrict__ w) {
    int k = blockIdx.x * 256 + threadIdx.x;
    unsigned long long k64 = 0ull;
    unsigned cnt = 0u;
    float sb = 0.f, sp = 0.f;
#pragma unroll
    for (int rp = 0; rp < 8; ++rp) {
        unsigned long long v = ((const unsigned long long*)w)[(rp << 10) + k];
        k64 = v > k64 ? v : k64;
        cnt += ((const unsigned*)w)[A_CNT + (rp << 10) + k];
        sb += w[A_SB + (rp << 10) + k];
        sp += w[A_SP + (rp << 10) + k];
    }
    bool ov = cnt > 0u;
    int ai = (int)(unsigned)(k64 & 0xffffffffull);
    float4 x0 = ((const float4*)coords)[ai * 2];
    float4 x1 = ((const float4*)coords)[ai * 2 + 1];
    float ba = beta[ai];
    float bca = fminf(fmaxf(ba, 0.f), 0.999f);
    float ata = atanhf(bca);
    float qa = ov ? ata * ata + 0.1f : 0.f;
    int rs1 = rs[1], rs2 = rs[2], rs3 = rs[3];
    int orr = (ai >= rs1) + (ai >= rs2) + (ai >= rs3);
    float cf = qa / fmaxf((float)cnt, 1.f);
    w[A_QA + k] = qa;
    w[A_CF + k] = cf;
    ((int*)w)[A_OR + k] = orr;
    ((float4*)(w + A_XLO))[k] = x0;
    ((float4*)(w + A_XHI))[k] = x1;
    w[A_PSM + k] = sp;
    ((unsigned*)w)[A_KEYM + k] = (unsigned)(k64 >> 32);
    w[A_SBM + k] = sb;
    ((unsigned*)w)[A_NKM + k] = cnt;
    if (ov) {
        atomicAdd(w + A_ACC + orr, 1.f);
        int slot = atomicAdd((int*)w + A_RC + orr, 1);
        int idx = (orr << 8) + slot;
        ((float4*)(w + A_CY0))[idx] = make_float4(-2.f * x0.x, -2.f * x0.y, -2.f * x0.z, -2.f * x0.w);
        ((float4*)(w + A_CY1))[idx] = make_float4(-2.f * x1.x, -2.f * x1.y, -2.f * x1.z, -2.f * x1.w);
        float ck2 = x0.x * x0.x + x0.y * x0.y + x0.z * x0.z + x0.w * x0.w +
                    x1.x * x1.x + x1.y * x1.y + x1.z * x1.z + x1.w * x1.w;
        ((float2*)(w + A_CCC))[idx] = make_float2(ck2 + 1e-6f, cf);
    }
}

// ---- P2: LSE sums only (replicated) ----
__global__ __launch_bounds__(512) void k_p2(const float* __restrict__ beta,
                                            const int* __restrict__ asso,
                                            float* __restrict__ w, int N) {
    int i = blockIdx.x * 512 + threadIdx.x;
    int rp = blockIdx.x & 7;
    if (i < N) {
        int a = asso[i];
        if (a >= 0) {
            float b = beta[i];
            float m = fdec(((const unsigned*)w)[A_KEYM + a]);
            atomicAdd(w + A_LSE + (rp << 10) + a, __expf((b - m) * 1000.f));
        }
    }
}

// ---- P4: N x K_row repulsion + fused epilogue ----
__global__ __launch_bounds__(512) void k_p4(const float* __restrict__ coords,
                                            const int* __restrict__ asso,
                                            const int* __restrict__ rs,
                                            const float* __restrict__ w,
                                            float* __restrict__ p6p,
                                            float* __restrict__ out, int N) {
    __shared__ float4 sY0[512];
    __shared__ float4 sY1[512];
    __shared__ float2 sCC[512];
    __shared__ float sBins[8];
    int t = threadIdx.x, bid = blockIdx.x;
    if (t < 8) sBins[t] = 0.f;
    int base = bid << 9;
    int rs1 = rs[1], rs2 = rs[2], rs3 = rs[3];
    int r0 = (base >= rs1) + (base >= rs2) + (base >= rs3);
    int lastp = min(base + 511, N - 1);
    int rl = (lastp >= rs1) + (lastp >= rs2) + (lastp >= rs3);
    const int* rc = (const int*)w + A_RC;
    int n0 = rc[r0];
    if (t < n0) {
        int idx = (r0 << 8) + t;
        sY0[t] = ((const float4*)(w + A_CY0))[idx];
        sY1[t] = ((const float4*)(w + A_CY1))[idx];
        sCC[t] = ((const float2*)(w + A_CCC))[idx];
    }
    int n1 = 0;
    if (rl != r0) {
        n1 = rc[rl];
        if (t < n1) {
            int idx = (rl << 8) + t;
            sY0[n0 + t] = ((const float4*)(w + A_CY0))[idx];
            sY1[n0 + t] = ((const float4*)(w + A_CY1))[idx];
            sCC[n0 + t] = ((const float2*)(w + A_CCC))[idx];
        }
    }
    __syncthreads();
    int i = base + t;
    float att = 0.f, rep = 0.f;
    int r = r0;
    if (i < N) {
        const float4* cp = (const float4*)(coords + (size_t)i * 8);
        float4 c0 = cp[0], c1 = cp[1];
        float cn2 = c0.x * c0.x + c0.y * c0.y + c0.z * c0.z + c0.w * c0.w +
                    c1.x * c1.x + c1.y * c1.y + c1.z * c1.z + c1.w * c1.w;
        r = (i >= rs1) + (i >= rs2) + (i >= rs3);
        int s = (r == r0) ? 0 : n0;
        int e = (r == r0) ? n0 : n0 + n1;
        float acc = 0.f;
#pragma unroll 2
        for (int j = s; j < e; ++j) {
            float4 y0 = sY0[j];
            float4 y1 = sY1[j];
            float2 cx = sCC[j];
            float d = cn2 + cx.x;
            d = fmaf(y0.x, c0.x, d); d = fmaf(y0.y, c0.y, d);
            d = fmaf(y0.z, c0.z, d); d = fmaf(y0.w, c0.w, d);
            d = fmaf(y1.x, c1.x, d); d = fmaf(y1.y, c1.y, d);
            d = fmaf(y1.z, c1.z, d); d = fmaf(y1.w, c1.w, d);
            d = fmaxf(d, 1e-6f);
            float v = fmaxf(1.f - sqrtf(d), 0.f);
            acc = fmaf(v, cx.y, acc);
        }
        int aa = asso[i];
        float q = w[A_QS + i];
        float pv = w[A_QS + N + i];
        bool valid = aa >= 0;
        int kk = valid ? aa : 0;
        if (valid) {
            float4 xk0 = ((const float4*)(w + A_XLO))[kk];
            float4 xk1 = ((const float4*)(w + A_XHI))[kk];
            float qak = w[A_QA + kk];
            float d0 = c0.x - xk0.x, d1 = c0.y - xk0.y, d2 = c0.z - xk0.z, d3 = c0.w - xk0.w;
            float d4 = c1.x - xk1.x, d5 = c1.y - xk1.y, d6 = c1.z - xk1.z, d7 = c1.w - xk1.w;
            float dsq = d0 * d0 + d1 * d1 + d2 * d2 + d3 * d3 +
                        d4 * d4 + d5 * d5 + d6 * d6 + d7 * d7;
            att = q * qak * dsq;
            int ork = ((const int*)w)[A_OR + kk];
            if (ork == r) {
                float ck2 = xk0.x * xk0.x + xk0.y * xk0.y + xk0.z * xk0.z + xk0.w * xk0.w +
                            xk1.x * xk1.x + xk1.y * xk1.y + xk1.z * xk1.z + xk1.w * xk1.w;
                float dotk = c0.x * xk0.x + c0.y * xk0.y + c0.z * xk0.z + c0.w * xk0.w +
                             c1.x * xk1.x + c1.y * xk1.y + c1.z * xk1.z + c1.w * xk1.w;
                float d = fmaxf(cn2 + ck2 - 2.f * dotk, 0.f) + 1e-6f;
                float vk = fmaxf(1.f - sqrtf(d), 0.f);
                acc -= vk * w[A_CF + kk];
            }
        }
        rep = q * acc;
        float psum = w[A_PSM + kk];
        float ocnt = w[A_ACC + r];
        float pl = valid ? pv / fmaxf(psum, 1e-6f) / fmaxf(ocnt, 1.f) * 0.25f : 0.f;
        out[3 + i] = pl;
        out[3 + N + i] = att + rep;
    }
    int lane = t & 63;
    int rA = __shfl(r, 0);
    bool uni = __all(r == rA);
    if (uni) {
        float aS = att, rS = rep;
#pragma unroll
        for (int o = 32; o; o >>= 1) { aS += __shfl_xor(aS, o); rS += __shfl_xor(rS, o); }
        if (lane == 0) { atomicAdd(&sBins[rA], aS); atomicAdd(&sBins[4 + rA], rS); }
    } else if (i < N) {
        atomicAdd(&sBins[r], att);
        atomicAdd(&sBins[4 + r], rep);
    }
    __syncthreads();
    if (t < 8) p6p[bid * 8 + t] = sBins[t];
}

// ---- P5: bpen per cluster + all final reductions (1 block, 1024 thr) ----
__global__ __launch_bounds__(1024) void k_p5(const int* __restrict__ rs,
                                             const float* __restrict__ w,
                                             const float* __restrict__ p6p, int nb,
                                             float* __restrict__ out) {
    __shared__ float op[4];
    __shared__ float ar8[8][9];
    __shared__ float nsb[8];
    int t = threadIdx.x;
    if (t < 4) op[t] = 0.f;
    // per-cluster beta penalty
    int k = t;
    float ls = 0.f;
#pragma unroll
    for (int rp = 0; rp < 8; ++rp) ls += w[A_LSE + (rp << 10) + k];
    unsigned cnt = ((const unsigned*)w)[A_NKM + k];
    bool ov = cnt > 0u;
    float m = ov ? fdec(((const unsigned*)w)[A_KEYM + k]) : 0.f;
    float lse = m + 0.001f * logf(ls + 1e-30f);
    float sbc = fminf(fmaxf(w[A_SBM + k], 0.f), 1.f);
    float bpen = ov ? (1.f - lse + (1.f - sbc)) : 0.f;
    int rowk = k >> 8;  // clusters are row-blocked by construction; !ov contribute 0
    // att/rep partial reduction
    if (t < 64) {
        int slot = t & 7, part = t >> 3;
        float acc = 0.f;
        for (int j = part; j < nb; j += 8) acc += p6p[j * 8 + slot];
        ar8[slot][part] = acc;
    }
    // noise merge
    if (t >= 64 && t < 72) {
        int j = t - 64;
        float a = 0.f;
#pragma unroll
        for (int rp = 0; rp < 8; ++rp) a += w[A_NS + rp * 8 + j];
        nsb[j] = a;
    }
    __syncthreads();
    float v = bpen;
#pragma unroll
    for (int o = 32; o; o >>= 1) v += __shfl_xor(v, o);
    if ((t & 63) == 0) atomicAdd(&op[rowk], v);
    __syncthreads();
    if (t == 0) {
        float lv = 0.f, lr = 0.f, lb = 0.f;
        for (int r = 0; r < B_RS; ++r) {
            float a = 0.f, rp = 0.f;
            for (int j = 0; j < 8; ++j) { a += ar8[r][j]; rp += ar8[4 + r][j]; }
            float len = (float)(rs[r + 1] - rs[r]);
            lv += a / len;
            lr += rp / len;
            float oc = w[A_ACC + r];
            lb += op[r] / fmaxf(oc, 1.f) + nsb[2 * r + 1] / fmaxf(nsb[2 * r], 1.f);
        }
        out[0] = lv * 0.25f;
        out[1] = lr * 0.25f;
        out[2] = lb * 0.25f;
    }
}

extern "C" void kernel_launch(void* const* d_in, const int* in_sizes, int n_in,
                              void* d_out, int out_size, void* d_ws, size_t ws_size,
                              hipStream_t stream) {
    const float* beta = (const float*)d_in[0];
    const float* coords = (const float*)d_in[1];
    const int* asso = (const int*)d_in[2];
    const int* rs = (const int*)d_in[3];
    int N = in_sizes[0];
    float* w = (float*)d_ws;
    float* out = (float*)d_out;
    int nb = (N + 511) / 512;
    float* p6p = w + A_QS + 2 * (size_t)N;
    hipLaunchKernelGGL(k_init, dim3(49), dim3(256), 0, stream, w);
    hipLaunchKernelGGL(k_p1, dim3(nb), dim3(512), 0, stream, beta, asso, rs, w, N);
    hipLaunchKernelGGL(k_m1, dim3(4), dim3(256), 0, stream, beta, coords, rs, w);
    hipLaunchKernelGGL(k_p2, dim3(nb), dim3(512), 0, stream, beta, asso, w, N);
    hipLaunchKernelGGL(k_p4, dim3(nb), dim3(512), 0, stream, coords, asso, rs, w, p6p, out, N);
    hipLaunchKernelGGL(k_p5, dim3(1), dim3(1024), 0, stream, rs, w, p6p, nb, out);
}